// Round 2
// baseline (157.895 us; speedup 1.0000x reference)
//
#include <hip/hip_runtime.h>

#define NJ 7
static constexpr float DT_C    = 0.01f;
static constexpr float G_ACC_C = 9.81f;

// E = (R_fix @ Rodrigues(axis,q))^T from sin/cos.
__device__ __forceinline__ void compute_E(const float* __restrict__ Rf,
                                          float ax, float ay, float az,
                                          float s, float c, float E[3][3]) {
    float oc = 1.0f - c;
    float K2xx = -(ay*ay + az*az);
    float K2yy = -(ax*ax + az*az);
    float K2zz = -(ax*ax + ay*ay);
    float K2xy = ax*ay, K2xz = ax*az, K2yz = ay*az;
    float R00 = 1.0f + oc*K2xx;
    float R01 = -s*az + oc*K2xy;
    float R02 =  s*ay + oc*K2xz;
    float R10 =  s*az + oc*K2xy;
    float R11 = 1.0f + oc*K2yy;
    float R12 = -s*ax + oc*K2yz;
    float R20 = -s*ay + oc*K2xz;
    float R21 =  s*ax + oc*K2yz;
    float R22 = 1.0f + oc*K2zz;
    E[0][0] = Rf[0]*R00 + Rf[1]*R10 + Rf[2]*R20;
    E[1][0] = Rf[0]*R01 + Rf[1]*R11 + Rf[2]*R21;
    E[2][0] = Rf[0]*R02 + Rf[1]*R12 + Rf[2]*R22;
    E[0][1] = Rf[3]*R00 + Rf[4]*R10 + Rf[5]*R20;
    E[1][1] = Rf[3]*R01 + Rf[4]*R11 + Rf[5]*R21;
    E[2][1] = Rf[3]*R02 + Rf[4]*R12 + Rf[5]*R22;
    E[0][2] = Rf[6]*R00 + Rf[7]*R10 + Rf[8]*R20;
    E[1][2] = Rf[6]*R01 + Rf[7]*R11 + Rf[8]*R21;
    E[2][2] = Rf[6]*R02 + Rf[7]*R12 + Rf[8]*R22;
}

extern "C" __global__ __launch_bounds__(256)
void aba_step_kernel(const float* __restrict__ x, const float* __restrict__ u,
                     const float* __restrict__ axes, const float* __restrict__ Rfix,
                     const float* __restrict__ pfix, const float* __restrict__ mass,
                     const float* __restrict__ com, const float* __restrict__ inertia,
                     float* __restrict__ out, int B)
{
    int b = blockIdx.x * blockDim.x + threadIdx.x;
    if (b >= B) return;

    float cl[NJ][6];   // Coriolis bias c_i (persists to pass 3)
    float pU[NJ][6];   // pA_i during fwd/bwd; then U_i/d_i (pre-scaled)
    float kk[NJ];      // uu_i / d_i

    // ---------------- pass 1: forward velocities ----------------
    {
        float xr[2*NJ];
        const float2* xv = (const float2*)(x + b*(2*NJ));  // rows are 8B-aligned (56B stride)
        #pragma unroll
        for (int k2 = 0; k2 < NJ; ++k2) { float2 t = xv[k2]; xr[2*k2] = t.x; xr[2*k2+1] = t.y; }

        float v0=0.f, v1=0.f, v2=0.f, v3=0.f, v4=0.f, v5=0.f;
        #pragma unroll
        for (int i = 0; i < NJ; ++i) {
            float s, c;
            __sincosf(xr[i], &s, &c);
            float ax = axes[3*i+0], ay = axes[3*i+1], az = axes[3*i+2];
            float qdi = xr[NJ+i];
            float vJ0 = qdi*ax, vJ1 = qdi*ay, vJ2 = qdi*az;
            if (i == 0) {
                v0 = vJ0; v1 = vJ1; v2 = vJ2; v3 = 0.f; v4 = 0.f; v5 = 0.f;
            } else {
                float E[3][3];
                compute_E(Rfix + 9*i, ax, ay, az, s, c, E);
                float px = pfix[3*i], py = pfix[3*i+1], pz = pfix[3*i+2];
                float t0 = v3 - (py*v2 - pz*v1);
                float t1 = v4 - (pz*v0 - px*v2);
                float t2 = v5 - (px*v1 - py*v0);
                float nw0 = E[0][0]*v0 + E[0][1]*v1 + E[0][2]*v2;
                float nw1 = E[1][0]*v0 + E[1][1]*v1 + E[1][2]*v2;
                float nw2 = E[2][0]*v0 + E[2][1]*v1 + E[2][2]*v2;
                float nu0 = E[0][0]*t0 + E[0][1]*t1 + E[0][2]*t2;
                float nu1 = E[1][0]*t0 + E[1][1]*t1 + E[1][2]*t2;
                float nu2 = E[2][0]*t0 + E[2][1]*t1 + E[2][2]*t2;
                v0 = nw0 + vJ0; v1 = nw1 + vJ1; v2 = nw2 + vJ2;
                v3 = nu0; v4 = nu1; v5 = nu2;
            }
            cl[i][0] = v1*vJ2 - v2*vJ1;
            cl[i][1] = v2*vJ0 - v0*vJ2;
            cl[i][2] = v0*vJ1 - v1*vJ0;
            cl[i][3] = v4*vJ2 - v5*vJ1;
            cl[i][4] = v5*vJ0 - v3*vJ2;
            cl[i][5] = v3*vJ1 - v4*vJ0;
            float m = mass[i];
            float cxx = com[3*i], cyy = com[3*i+1], czz = com[3*i+2];
            const float* In = inertia + 9*i;
            float ccm = cxx*cxx + cyy*cyy + czz*czz;
            float A00 = In[0] + m*(ccm - cxx*cxx);
            float A01 = In[1] - m*cxx*cyy;
            float A02 = In[2] - m*cxx*czz;
            float A11 = In[4] + m*(ccm - cyy*cyy);
            float A12 = In[5] - m*cyy*czz;
            float A22 = In[8] + m*(ccm - czz*czz);
            float n0 = A00*v0 + A01*v1 + A02*v2 + m*(cyy*v5 - czz*v4);
            float n1 = A01*v0 + A11*v1 + A12*v2 + m*(czz*v3 - cxx*v5);
            float n2 = A02*v0 + A12*v1 + A22*v2 + m*(cxx*v4 - cyy*v3);
            float f0 = m*(v1*czz - v2*cyy + v3);
            float f1 = m*(v2*cxx - v0*czz + v4);
            float f2 = m*(v0*cyy - v1*cxx + v5);
            pU[i][0] = v1*n2 - v2*n1 + v4*f2 - v5*f1;
            pU[i][1] = v2*n0 - v0*n2 + v5*f0 - v3*f2;
            pU[i][2] = v0*n1 - v1*n0 + v3*f1 - v4*f0;
            pU[i][3] = v1*f2 - v2*f1;
            pU[i][4] = v2*f0 - v0*f2;
            pU[i][5] = v0*f1 - v1*f0;
        }
    }

    // ---------------- pass 2: backward (symmetric 6x6 blocks) ----------------
    // P = [[PA (sym), PB],[PB^T, PC (sym)]]; sym order {00,01,02,11,12,22}
    float PA[6], PB[9], PC[6];
    #pragma unroll
    for (int r = 0; r < 6; ++r) { PA[r] = 0.f; PC[r] = 0.f; }
    #pragma unroll
    for (int r = 0; r < 9; ++r) PB[r] = 0.f;

    #pragma unroll
    for (int ii = 0; ii < NJ; ++ii) {
        const int i = NJ - 1 - ii;
        float m = mass[i];
        float cx = com[3*i], cy = com[3*i+1], cz = com[3*i+2];
        const float* In = inertia + 9*i;   // assumes symmetric inertia (true for rigid bodies)
        float ccm = cx*cx + cy*cy + cz*cz;
        float A0 = In[0] + m*(ccm - cx*cx) + PA[0];
        float A1 = In[1] - m*cx*cy         + PA[1];
        float A2 = In[2] - m*cx*cz         + PA[2];
        float A3 = In[4] + m*(ccm - cy*cy) + PA[3];
        float A4 = In[5] - m*cy*cz         + PA[4];
        float A5 = In[8] + m*(ccm - cz*cz) + PA[5];
        float B00 = PB[0];          float B01 = -m*cz + PB[1]; float B02 =  m*cy + PB[2];
        float B10 =  m*cz + PB[3];  float B11 = PB[4];         float B12 = -m*cx + PB[5];
        float B20 = -m*cy + PB[6];  float B21 =  m*cx + PB[7]; float B22 = PB[8];
        float C0 = m + PC[0], C1 = PC[1], C2 = PC[2];
        float C3 = m + PC[3], C4 = PC[4], C5 = m + PC[5];

        float ax = axes[3*i], ay = axes[3*i+1], az = axes[3*i+2];
        float Ua0 = A0*ax + A1*ay + A2*az;
        float Ua1 = A1*ax + A3*ay + A4*az;
        float Ua2 = A2*ax + A4*ay + A5*az;
        float Ul0 = B00*ax + B10*ay + B20*az;
        float Ul1 = B01*ax + B11*ay + B21*az;
        float Ul2 = B02*ax + B12*ay + B22*az;
        float d  = Ua0*ax + Ua1*ay + Ua2*az;
        float uu = u[b*NJ + i] - (pU[i][0]*ax + pU[i][1]*ay + pU[i][2]*az);
        float invd = __builtin_amdgcn_rcpf(d);
        float k = uu * invd;
        float t0 = Ua0*invd, t1 = Ua1*invd, t2 = Ua2*invd;
        float t3 = Ul0*invd, t4 = Ul1*invd, t5 = Ul2*invd;

        if (i > 0) {
            // Ia = IA - U (U/d)^T  (symmetric blocks)
            A0 -= Ua0*t0; A1 -= Ua0*t1; A2 -= Ua0*t2;
            A3 -= Ua1*t1; A4 -= Ua1*t2; A5 -= Ua2*t2;
            B00 -= Ua0*t3; B01 -= Ua0*t4; B02 -= Ua0*t5;
            B10 -= Ua1*t3; B11 -= Ua1*t4; B12 -= Ua1*t5;
            B20 -= Ua2*t3; B21 -= Ua2*t4; B22 -= Ua2*t5;
            C0 -= Ul0*t3; C1 -= Ul0*t4; C2 -= Ul0*t5;
            C3 -= Ul1*t4; C4 -= Ul1*t5; C5 -= Ul2*t5;

            float ca0 = cl[i][0], ca1 = cl[i][1], ca2 = cl[i][2];
            float cb0 = cl[i][3], cb1 = cl[i][4], cb2 = cl[i][5];
            float pa0 = pU[i][0] + A0*ca0 + A1*ca1 + A2*ca2 + B00*cb0 + B01*cb1 + B02*cb2 + Ua0*k;
            float pa1 = pU[i][1] + A1*ca0 + A3*ca1 + A4*ca2 + B10*cb0 + B11*cb1 + B12*cb2 + Ua1*k;
            float pa2 = pU[i][2] + A2*ca0 + A4*ca1 + A5*ca2 + B20*cb0 + B21*cb1 + B22*cb2 + Ua2*k;
            float pa3 = pU[i][3] + B00*ca0 + B10*ca1 + B20*ca2 + C0*cb0 + C1*cb1 + C2*cb2 + Ul0*k;
            float pa4 = pU[i][4] + B01*ca0 + B11*ca1 + B21*ca2 + C1*cb0 + C3*cb1 + C4*cb2 + Ul1*k;
            float pa5 = pU[i][5] + B02*ca0 + B12*ca1 + B22*ca2 + C2*cb0 + C4*cb1 + C5*cb2 + Ul2*k;

            float s, c;
            __sincosf(x[b*(2*NJ) + i], &s, &c);
            float E[3][3];
            compute_E(Rfix + 9*i, ax, ay, az, s, c, E);
            float px = pfix[3*i], py = pfix[3*i+1], pz = pfix[3*i+2];
            float F[3][3];   // F = -E @ skew(p)
            #pragma unroll
            for (int r = 0; r < 3; ++r) {
                F[r][0] = E[r][2]*py - E[r][1]*pz;
                F[r][1] = E[r][0]*pz - E[r][2]*px;
                F[r][2] = E[r][1]*px - E[r][0]*py;
            }

            // temps: BE = B*E, CEm = C*E (C sym)
            float BE[3][3], CEm[3][3];
            #pragma unroll
            for (int c2 = 0; c2 < 3; ++c2) {
                BE[0][c2]  = B00*E[0][c2] + B01*E[1][c2] + B02*E[2][c2];
                BE[1][c2]  = B10*E[0][c2] + B11*E[1][c2] + B12*E[2][c2];
                BE[2][c2]  = B20*E[0][c2] + B21*E[1][c2] + B22*E[2][c2];
                CEm[0][c2] = C0*E[0][c2] + C1*E[1][c2] + C2*E[2][c2];
                CEm[1][c2] = C1*E[0][c2] + C3*E[1][c2] + C4*E[2][c2];
                CEm[2][c2] = C2*E[0][c2] + C4*E[1][c2] + C5*E[2][c2];
            }
            // P'B = E^T*BE + F^T*CEm (full 3x3)
            #pragma unroll
            for (int r = 0; r < 3; ++r)
                #pragma unroll
                for (int c2 = 0; c2 < 3; ++c2)
                    PB[3*r+c2] = E[0][r]*BE[0][c2] + E[1][r]*BE[1][c2] + E[2][r]*BE[2][c2]
                               + F[0][r]*CEm[0][c2] + F[1][r]*CEm[1][c2] + F[2][r]*CEm[2][c2];
            // P'C = E^T*CEm (symmetric upper)
            {
                int idx = 0;
                #pragma unroll
                for (int r = 0; r < 3; ++r)
                    #pragma unroll
                    for (int c2 = r; c2 < 3; ++c2, ++idx)
                        PC[idx] = E[0][r]*CEm[0][c2] + E[1][r]*CEm[1][c2] + E[2][r]*CEm[2][c2];
            }
            // W1 = A*E + B*F ; W2 = B^T*E + C*F
            float W1[3][3], W2[3][3];
            #pragma unroll
            for (int c2 = 0; c2 < 3; ++c2) {
                W1[0][c2] = A0*E[0][c2] + A1*E[1][c2] + A2*E[2][c2] + B00*F[0][c2] + B01*F[1][c2] + B02*F[2][c2];
                W1[1][c2] = A1*E[0][c2] + A3*E[1][c2] + A4*E[2][c2] + B10*F[0][c2] + B11*F[1][c2] + B12*F[2][c2];
                W1[2][c2] = A2*E[0][c2] + A4*E[1][c2] + A5*E[2][c2] + B20*F[0][c2] + B21*F[1][c2] + B22*F[2][c2];
                W2[0][c2] = B00*E[0][c2] + B10*E[1][c2] + B20*E[2][c2] + C0*F[0][c2] + C1*F[1][c2] + C2*F[2][c2];
                W2[1][c2] = B01*E[0][c2] + B11*E[1][c2] + B21*E[2][c2] + C1*F[0][c2] + C3*F[1][c2] + C4*F[2][c2];
                W2[2][c2] = B02*E[0][c2] + B12*E[1][c2] + B22*E[2][c2] + C2*F[0][c2] + C4*F[1][c2] + C5*F[2][c2];
            }
            // P'A = E^T*W1 + F^T*W2 (symmetric upper)
            {
                int idx = 0;
                #pragma unroll
                for (int r = 0; r < 3; ++r)
                    #pragma unroll
                    for (int c2 = r; c2 < 3; ++c2, ++idx)
                        PA[idx] = E[0][r]*W1[0][c2] + E[1][r]*W1[1][c2] + E[2][r]*W1[2][c2]
                                + F[0][r]*W2[0][c2] + F[1][r]*W2[1][c2] + F[2][r]*W2[2][c2];
            }
            // pA_{i-1} += [E^T pa_ang + p x fE ; fE]
            float fE0 = E[0][0]*pa3 + E[1][0]*pa4 + E[2][0]*pa5;
            float fE1 = E[0][1]*pa3 + E[1][1]*pa4 + E[2][1]*pa5;
            float fE2 = E[0][2]*pa3 + E[1][2]*pa4 + E[2][2]*pa5;
            float nP0 = E[0][0]*pa0 + E[1][0]*pa1 + E[2][0]*pa2 + (py*fE2 - pz*fE1);
            float nP1 = E[0][1]*pa0 + E[1][1]*pa1 + E[2][1]*pa2 + (pz*fE0 - px*fE2);
            float nP2 = E[0][2]*pa0 + E[1][2]*pa1 + E[2][2]*pa2 + (px*fE1 - py*fE0);
            pU[i-1][0] += nP0; pU[i-1][1] += nP1; pU[i-1][2] += nP2;
            pU[i-1][3] += fE0; pU[i-1][4] += fE1; pU[i-1][5] += fE2;
        }
        // store pre-scaled U/d; qdd_i = kk[i] - dot6(pU[i], ap)
        pU[i][0] = t0; pU[i][1] = t1; pU[i][2] = t2;
        pU[i][3] = t3; pU[i][4] = t4; pU[i][5] = t5;
        kk[i] = k;
    }

    // ---------------- pass 3: forward accelerations + integrate ----------------
    {
        float xr[2*NJ];
        const float2* xv = (const float2*)(x + b*(2*NJ));
        #pragma unroll
        for (int k2 = 0; k2 < NJ; ++k2) { float2 t = xv[k2]; xr[2*k2] = t.x; xr[2*k2+1] = t.y; }

        float o[2*NJ];
        float a0=0.f, a1=0.f, a2=0.f, a3=0.f, a4=0.f, a5=G_ACC_C;
        #pragma unroll
        for (int i = 0; i < NJ; ++i) {
            float s, c;
            __sincosf(xr[i], &s, &c);
            float ax = axes[3*i], ay = axes[3*i+1], az = axes[3*i+2];
            float E[3][3];
            compute_E(Rfix + 9*i, ax, ay, az, s, c, E);
            float px = pfix[3*i], py = pfix[3*i+1], pz = pfix[3*i+2];
            float t0 = a3 - (py*a2 - pz*a1);
            float t1 = a4 - (pz*a0 - px*a2);
            float t2 = a5 - (px*a1 - py*a0);
            float ap0 = E[0][0]*a0 + E[0][1]*a1 + E[0][2]*a2 + cl[i][0];
            float ap1 = E[1][0]*a0 + E[1][1]*a1 + E[1][2]*a2 + cl[i][1];
            float ap2 = E[2][0]*a0 + E[2][1]*a1 + E[2][2]*a2 + cl[i][2];
            float ap3 = E[0][0]*t0 + E[0][1]*t1 + E[0][2]*t2 + cl[i][3];
            float ap4 = E[1][0]*t0 + E[1][1]*t1 + E[1][2]*t2 + cl[i][4];
            float ap5 = E[2][0]*t0 + E[2][1]*t1 + E[2][2]*t2 + cl[i][5];
            float qdd = kk[i] - (pU[i][0]*ap0 + pU[i][1]*ap1 + pU[i][2]*ap2
                               + pU[i][3]*ap3 + pU[i][4]*ap4 + pU[i][5]*ap5);
            a0 = ap0 + qdd*ax; a1 = ap1 + qdd*ay; a2 = ap2 + qdd*az;
            a3 = ap3; a4 = ap4; a5 = ap5;
            float vn = xr[NJ+i] + DT_C*qdd;
            o[NJ+i] = vn;
            o[i]    = xr[i] + DT_C*vn;
        }
        float2* ov = (float2*)(out + b*(2*NJ));
        #pragma unroll
        for (int k2 = 0; k2 < NJ; ++k2) { float2 t; t.x = o[2*k2]; t.y = o[2*k2+1]; ov[k2] = t; }
    }
}

extern "C" void kernel_launch(void* const* d_in, const int* in_sizes, int n_in,
                              void* d_out, int out_size, void* d_ws, size_t ws_size,
                              hipStream_t stream) {
    const float* x       = (const float*)d_in[0];
    const float* u       = (const float*)d_in[1];
    const float* axes    = (const float*)d_in[2];
    const float* Rfix    = (const float*)d_in[3];
    const float* pfix    = (const float*)d_in[4];
    const float* mass    = (const float*)d_in[5];
    const float* com     = (const float*)d_in[6];
    const float* inertia = (const float*)d_in[7];
    float* out = (float*)d_out;
    int B = in_sizes[0] / (2*NJ);
    int threads = 256;
    int blocks = (B + threads - 1) / threads;
    hipLaunchKernelGGL(aba_step_kernel, dim3(blocks), dim3(threads), 0, stream,
                       x, u, axes, Rfix, pfix, mass, com, inertia, out, B);
}